// Round 17
// baseline (119.883 us; speedup 1.0000x reference)
//
#include <hip/hip_runtime.h>
#include <hip/hip_bf16.h>

#define B_ 4
#define Q_ 512
#define K_ 512
#define DQ_ 512
#define H_ 256
#define DV_ 512

#define SC2 2.8853900817779268f   // 2*log2(e): exp(2x) = exp2(SC2*x)

typedef unsigned short u16;
typedef short bf16x8 __attribute__((ext_vector_type(8)));
typedef float f32x4 __attribute__((ext_vector_type(4)));
typedef float f32x2 __attribute__((ext_vector_type(2)));
typedef unsigned short u16x4 __attribute__((ext_vector_type(4)));

// split fp32 a into bf16 hi/lo (RN both): a ~= hi + lo, packed [hi16|lo16]
__device__ __forceinline__ unsigned bsplit(float a) {
    unsigned u  = __float_as_uint(a);
    unsigned hi = (u + 0x7FFFu + ((u >> 16) & 1u)) >> 16;
    float hf = __uint_as_float(hi << 16);
    float l  = a - hf;
    unsigned ul = __float_as_uint(l);
    unsigned lo = (ul + 0x7FFFu + ((ul >> 16) & 1u)) >> 16;
    return (hi << 16) | lo;
}

// RN fp32 -> bf16 (hi only)
__device__ __forceinline__ u16 brn(float a) {
    unsigned u = __float_as_uint(a);
    return (u16)((u + 0x7FFFu + ((u >> 16) & 1u)) >> 16);
}

__device__ __forceinline__ void gld16(const void* g, void* l) {
    __builtin_amdgcn_global_load_lds(
        (const __attribute__((address_space(1))) unsigned int*)g,
        (__attribute__((address_space(3))) unsigned int*)l, 16, 0, 0);
}

// pair of h-terms over common denominator:
// w0/(1+e0) + w1/(1+e1) = (w01 + w0*e1 + w1*e0) / (1 + e0 + e1 + e0*e1)
__device__ __forceinline__ void pair_acc(
    f32x2 Eq0, f32x2 Eq1, float ek0, float ek1,
    float w0, float w1, float w01, f32x2& acc)
{
    f32x2 e0 = Eq0 * (f32x2){ek0, ek0};                       // v_pk_mul_f32
    f32x2 e1 = Eq1 * (f32x2){ek1, ek1};
    f32x2 s  = e0 + e1;                                       // v_pk_add_f32
    f32x2 den = __builtin_elementwise_fma(e0, e1, s);         // e0e1+e0+e1
    den = den + (f32x2){1.f, 1.f};
    f32x2 num = __builtin_elementwise_fma(e1, (f32x2){w0, w0}, (f32x2){w01, w01});
    num = __builtin_elementwise_fma(e0, (f32x2){w1, w1}, num);
    f32x2 r = {__builtin_amdgcn_rcpf(den.x), __builtin_amdgcn_rcpf(den.y)};
    acc = __builtin_elementwise_fma(num, r, acc);
}

// ============ merged prep: rows-convert + transposes in ONE launch ============
__global__ __launch_bounds__(256) void prep_all(
    const float* __restrict__ query, const float* __restrict__ key,
    const float* __restrict__ Wq, const float* __restrict__ Wk,
    const float* __restrict__ value,
    u16* __restrict__ qA_hi, u16* __restrict__ qA_lo,
    u16* __restrict__ WT_hi, u16* __restrict__ WT_lo,
    u16* __restrict__ vT_hi)
{
    const int bx  = blockIdx.x;
    const int tid = threadIdx.x;

    if (bx < 2048) {
        const int z = bx >> 10;
        const float* src = z ? key : query;
        u16* dh = qA_hi + (long long)z * 1048576;
        u16* dl = qA_lo + (long long)z * 1048576;
        long long i4 = (long long)(bx & 1023) * 256 + tid;
        float4 v = ((const float4*)src)[i4];
        unsigned a = bsplit(v.x), b = bsplit(v.y), c = bsplit(v.z), d = bsplit(v.w);
        u16x4 h4 = {(u16)(a >> 16), (u16)(b >> 16), (u16)(c >> 16), (u16)(d >> 16)};
        u16x4 l4 = {(u16)(a & 0xFFFF), (u16)(b & 0xFFFF), (u16)(c & 0xFFFF), (u16)(d & 0xFFFF)};
        *(u16x4*)(dh + i4 * 4) = h4;
        *(u16x4*)(dl + i4 * 4) = l4;
        return;
    }

    __shared__ float t[32][33];
    const int flat = bx - 2048;
    const int z  = flat >> 8;            // 0..5
    const int rem = flat & 255;
    const int gx = rem & 15, gy = rem >> 4;
    const int x = tid & 31, y = tid >> 5;
    const float* src; u16 *dh, *dl; int C;
    if (z < 2) {
        if (gy >= 8) return;
        src = z ? Wk : Wq; C = 256;
        dh = WT_hi + (long long)z * 131072;
        dl = WT_lo + (long long)z * 131072;
    } else {
        src = value + (long long)(z - 2) * 262144; C = 512;
        dh = vT_hi + (long long)(z - 2) * 262144;
        dl = nullptr;                    // value: bf16 hi only (PV is 1-MFMA)
    }
    const int r0 = gx * 32, c0 = gy * 32;
    #pragma unroll
    for (int i = 0; i < 32; i += 8)
        t[y + i][x] = src[(long long)(r0 + y + i) * C + c0 + x];
    __syncthreads();
    {
        const int r = tid >> 3, c = tid & 7;
        long long o = (long long)(c0 + r) * 512 + r0 + 4 * c;
        if (dl) {
            unsigned p0 = bsplit(t[4 * c + 0][r]);
            unsigned p1 = bsplit(t[4 * c + 1][r]);
            unsigned p2 = bsplit(t[4 * c + 2][r]);
            unsigned p3 = bsplit(t[4 * c + 3][r]);
            u16x4 h4 = {(u16)(p0 >> 16), (u16)(p1 >> 16), (u16)(p2 >> 16), (u16)(p3 >> 16)};
            u16x4 l4 = {(u16)(p0 & 0xFFFF), (u16)(p1 & 0xFFFF), (u16)(p2 & 0xFFFF), (u16)(p3 & 0xFFFF)};
            *(u16x4*)(dh + o) = h4;
            *(u16x4*)(dl + o) = l4;
        } else {
            u16x4 h4 = {brn(t[4 * c + 0][r]), brn(t[4 * c + 1][r]),
                        brn(t[4 * c + 2][r]), brn(t[4 * c + 3][r])};
            *(u16x4*)(dh + o) = h4;
        }
    }
}

// ============ bf16x3 MFMA proj GEMM — 2-phase double-buffered LDS ============
__global__ __launch_bounds__(256) void proj_gemm(
    const u16* __restrict__ Ah0, const u16* __restrict__ Al0,
    const u16* __restrict__ Bh0, const u16* __restrict__ Bl0,
    const float* __restrict__ biasq, const float* __restrict__ biask,
    float* __restrict__ outp,
    long long sA, long long sB, long long sO)
{
    const int z = blockIdx.z;
    const int Kd = DQ_;
    const u16* Ah = Ah0 + z * sA;
    const u16* Al = Al0 + z * sA;
    const u16* Bh = Bh0 + z * sB;
    const u16* Bl = Bl0 + z * sB;

    const int m0 = blockIdx.x * 64;
    const int n0 = blockIdx.y * 64;

    __shared__ u16 AhS[2][64 * 64], AlS[2][64 * 64], BhS[2][64 * 64], BlS[2][64 * 64];

    const int tid = threadIdx.x;
    const int lane = tid & 63, w = tid >> 6;
    const int wr = w >> 1, wc = w & 1;
    const int lrow = lane & 15, lgrp = lane >> 4;

    f32x4 acc[2][2] = {};

    const int idx0 = tid, idx1 = tid + 256;
    const int row0 = idx0 >> 3, u0 = idx0 & 7;
    const int row1 = idx1 >> 3, u1 = idx1 & 7;
    const long long goA0 = (long long)(m0 + row0) * Kd + ((u0 ^ (row0 & 7)) << 3);
    const long long goA1 = (long long)(m0 + row1) * Kd + ((u1 ^ (row1 & 7)) << 3);
    const long long goB0 = (long long)(n0 + row0) * Kd + ((u0 ^ (row0 & 7)) << 3);
    const long long goB1 = (long long)(n0 + row1) * Kd + ((u1 ^ (row1 & 7)) << 3);

#define STAGE(BI, K0) do {                                    \
        gld16(Ah + goA0 + (K0), &AhS[BI][idx0 * 8]);          \
        gld16(Al + goA0 + (K0), &AlS[BI][idx0 * 8]);          \
        gld16(Bh + goB0 + (K0), &BhS[BI][idx0 * 8]);          \
        gld16(Bl + goB0 + (K0), &BlS[BI][idx0 * 8]);          \
        gld16(Ah + goA1 + (K0), &AhS[BI][idx1 * 8]);          \
        gld16(Al + goA1 + (K0), &AlS[BI][idx1 * 8]);          \
        gld16(Bh + goB1 + (K0), &BhS[BI][idx1 * 8]);          \
        gld16(Bl + goB1 + (K0), &BlS[BI][idx1 * 8]);          \
    } while (0)

    STAGE(0, 0);
    __syncthreads();

    int cur = 0;
    for (int k0 = 0; k0 < Kd; k0 += 64) {
        if (k0 + 64 < Kd) STAGE(cur ^ 1, k0 + 64);

        #pragma unroll
        for (int kk = 0; kk < 2; ++kk) {
            bf16x8 ah[2], al[2], bh[2], bl[2];
            #pragma unroll
            for (int f = 0; f < 2; ++f) {
                int ar = wr * 32 + f * 16 + lrow;
                int au = (kk * 4 + lgrp) ^ (ar & 7);
                ah[f] = *(const bf16x8*)(&AhS[cur][ar * 64 + au * 8]);
                al[f] = *(const bf16x8*)(&AlS[cur][ar * 64 + au * 8]);
                int br = wc * 32 + f * 16 + lrow;
                int bu = (kk * 4 + lgrp) ^ (br & 7);
                bh[f] = *(const bf16x8*)(&BhS[cur][br * 64 + bu * 8]);
                bl[f] = *(const bf16x8*)(&BlS[cur][br * 64 + bu * 8]);
            }
            #pragma unroll
            for (int fm = 0; fm < 2; ++fm)
                #pragma unroll
                for (int fn = 0; fn < 2; ++fn) {
                    acc[fm][fn] = __builtin_amdgcn_mfma_f32_16x16x32_bf16(ah[fm], bh[fn], acc[fm][fn], 0, 0, 0);
                    acc[fm][fn] = __builtin_amdgcn_mfma_f32_16x16x32_bf16(ah[fm], bl[fn], acc[fm][fn], 0, 0, 0);
                    acc[fm][fn] = __builtin_amdgcn_mfma_f32_16x16x32_bf16(al[fm], bh[fn], acc[fm][fn], 0, 0, 0);
                }
        }
        __syncthreads();
        cur ^= 1;
    }
#undef STAGE

    const float* bs = z ? biask : biasq;
    #pragma unroll
    for (int fm = 0; fm < 2; ++fm)
        #pragma unroll
        for (int fn = 0; fn < 2; ++fn)
            #pragma unroll
            for (int r = 0; r < 4; ++r) {
                int m = m0 + wr * 32 + fm * 16 + lgrp * 4 + r;
                int n = n0 + wc * 32 + fn * 16 + lrow;
                float v = __builtin_amdgcn_exp2f((acc[fm][fn][r] + bs[n]) * SC2);
                if (z == 0) {
                    outp[(((long long)(m >> 2) * H_ + n) << 2) + (m & 3)] = v;
                } else {
                    int bb = m >> 9, k = m & 511;
                    outp[sO + (((long long)(bb * 64 + (n >> 2)) * 512 + k) << 2) + (n & 3)] = v;
                }
            }
}

// ============ PV GEMM — single bf16 MFMA ============
__global__ __launch_bounds__(256) void pv_gemm(
    const u16* __restrict__ A0, const u16* __restrict__ B0,
    float* __restrict__ ctx)
{
    const int z = blockIdx.z;
    const int Kd = K_;
    const u16* A = A0 + (long long)z * 262144;
    const u16* Bp = B0 + (long long)z * 262144;
    float* C = ctx + (long long)z * 262144;

    const int m0 = blockIdx.x * 64;
    const int n0 = blockIdx.y * 64;

    __shared__ u16 AS[2][64 * 64], BS[2][64 * 64];

    const int tid = threadIdx.x;
    const int lane = tid & 63, w = tid >> 6;
    const int wr = w >> 1, wc = w & 1;
    const int lrow = lane & 15, lgrp = lane >> 4;

    f32x4 acc[2][2] = {};

    const int idx0 = tid, idx1 = tid + 256;
    const int row0 = idx0 >> 3, u0 = idx0 & 7;
    const int row1 = idx1 >> 3, u1 = idx1 & 7;
    const long long goA0 = (long long)(m0 + row0) * Kd + ((u0 ^ (row0 & 7)) << 3);
    const long long goA1 = (long long)(m0 + row1) * Kd + ((u1 ^ (row1 & 7)) << 3);
    const long long goB0 = (long long)(n0 + row0) * Kd + ((u0 ^ (row0 & 7)) << 3);
    const long long goB1 = (long long)(n0 + row1) * Kd + ((u1 ^ (row1 & 7)) << 3);

#define STAGE(BI, K0) do {                                    \
        gld16(A  + goA0 + (K0), &AS[BI][idx0 * 8]);           \
        gld16(Bp + goB0 + (K0), &BS[BI][idx0 * 8]);           \
        gld16(A  + goA1 + (K0), &AS[BI][idx1 * 8]);           \
        gld16(Bp + goB1 + (K0), &BS[BI][idx1 * 8]);           \
    } while (0)

    STAGE(0, 0);
    __syncthreads();

    int cur = 0;
    for (int k0 = 0; k0 < Kd; k0 += 64) {
        if (k0 + 64 < Kd) STAGE(cur ^ 1, k0 + 64);

        #pragma unroll
        for (int kk = 0; kk < 2; ++kk) {
            bf16x8 a[2], b[2];
            #pragma unroll
            for (int f = 0; f < 2; ++f) {
                int ar = wr * 32 + f * 16 + lrow;
                int au = (kk * 4 + lgrp) ^ (ar & 7);
                a[f] = *(const bf16x8*)(&AS[cur][ar * 64 + au * 8]);
                int br = wc * 32 + f * 16 + lrow;
                int bu = (kk * 4 + lgrp) ^ (br & 7);
                b[f] = *(const bf16x8*)(&BS[cur][br * 64 + bu * 8]);
            }
            #pragma unroll
            for (int fm = 0; fm < 2; ++fm)
                #pragma unroll
                for (int fn = 0; fn < 2; ++fn)
                    acc[fm][fn] = __builtin_amdgcn_mfma_f32_16x16x32_bf16(a[fm], b[fn], acc[fm][fn], 0, 0, 0);
        }
        __syncthreads();
        cur ^= 1;
    }
#undef STAGE

    #pragma unroll
    for (int fm = 0; fm < 2; ++fm)
        #pragma unroll
        for (int fn = 0; fn < 2; ++fn)
            #pragma unroll
            for (int r = 0; r < 4; ++r) {
                int m = m0 + wr * 32 + fm * 16 + lgrp * 4 + r;
                int n = n0 + wc * 32 + fn * 16 + lrow;
                C[(long long)m * DV_ + n] = acc[fm][fn][r];
            }
}

// ============ fused score + softmax: QT=8 (R16 version, unchanged) ============
#define QT 8

__global__ __launch_bounds__(1024) void score_softmax(
    const float* __restrict__ qp4E, // [(B*Q)/4][H][4] = exp2(SC2*qproj)
    const float* __restrict__ kT4E, // [B][H/4][K][4]  = exp2(SC2*kproj)
    const float* __restrict__ wv,   // [H]
    float* __restrict__ attn_out,   // [B*Q][K] fp32
    u16* __restrict__ aB_hi)        // attn bf16 for PV
{
    const int b   = blockIdx.y;
    const int q0  = blockIdx.x * QT;
    const int tid = threadIdx.x;          // 0..1023
    const int k16 = tid & 255;
    const int qtr = tid >> 8;             // h-quarter 0..3
    const int lane = tid & 63;

    __shared__ float lq[H_][8];           // Eq broadcast: [h][q 0..7] (8KB)
    __shared__ float lwp[H_ / 2][4];      // {w0,w1,w0+w1,0} per h-pair (2KB)
    __shared__ float pacc[3][2][256][8];  // 48KB: [quarter-1][kk][k16][qq]
    __shared__ float red[4][QT];          // 128B

    if (tid < 256) {
        const float4* qA = (const float4*)qp4E + ((long long)(b * (Q_ / 4) + 2 * blockIdx.x)) * H_;
        *(float4*)&lq[tid][0] = qA[tid];
    } else if (tid < 512) {
        int h = tid - 256;
        const float4* qB = (const float4*)qp4E + ((long long)(b * (Q_ / 4) + 2 * blockIdx.x + 1)) * H_;
        *(float4*)&lq[h][4] = qB[h];
    } else if (tid < 512 + 128) {
        int p = tid - 512;
        float w0 = wv[2 * p], w1 = wv[2 * p + 1];
        lwp[p][0] = w0; lwp[p][1] = w1; lwp[p][2] = w0 + w1; lwp[p][3] = 0.f;
    }
    __syncthreads();

    f32x2 aA[4] = {{0.f,0.f},{0.f,0.f},{0.f,0.f},{0.f,0.f}};
    f32x2 aB[4] = {{0.f,0.f},{0.f,0.f},{0.f,0.f},{0.f,0.f}};
    const float4* kvec = (const float4*)kT4E + (long long)b * (H_ / 4) * K_ + k16;
    const int g0 = qtr * 16;

    float4 kA = kvec[(long long)g0 * K_];
    float4 kB = kvec[(long long)g0 * K_ + 256];
    #pragma unroll 2
    for (int gi = 0; gi < 16; ++gi) {
        const int g = g0 + gi;
        float4 kAc = kA, kBc = kB;
        if (gi < 15) {                                  // 1-deep prefetch
            kA = kvec[(long long)(g + 1) * K_];
            kB = kvec[(long long)(g + 1) * K_ + 256];
        }
        float4 wp0 = *(const float4*)&lwp[(g << 1) + 0][0];
        float4 wp1 = *(const float4*)&lwp[(g << 1) + 1][0];

        float4 qa0 = *(const float4*)&lq[(g << 2) + 0][0];
        float4 qb0 = *(const float4*)&lq[(g << 2) + 0][4];
        float4 qa1 = *(const float4*)&lq[(g << 2) + 1][0];
        float4 qb1 = *(const float4*)&lq[(g << 2) + 1][4];
        float4 qa2 = *(const float4*)&lq[(g << 2) + 2][0];
        float4 qb2 = *(const float4*)&lq[(g << 2) + 2][4];
        float4 qa3 = *(const float4*)&lq[(g << 2) + 3][0];
        float4 qb3 = *(const float4*)&lq[(g << 2) + 3][4];

        f32x2 q0p[4] = {{qa0.x,qa0.y},{qa0.z,qa0.w},{qb0.x,qb0.y},{qb0.z,qb0.w}};
        f32x2 q1p[4] = {{qa1.x,qa1.y},{qa1.z,qa1.w},{qb1.x,qb1.y},{qb1.z,qb1.w}};
        f32x2 q2p[4] = {{qa2.x,qa2.y},{qa2.z,qa2.w},{qb2.x,qb2.y},{qb2.z,qb2.w}};
        f32x2 q3p[4] = {{qa3.x,qa3.y},{qa3.z,qa3.w},{qb3.x,qb3.y},{qb3.z,qb3.w}};

        #pragma unroll
        for (int qp = 0; qp < 4; ++qp) {
            pair_acc(q0p[qp], q1p[qp], kAc.x, kAc.y, wp0.x, wp0.y, wp0.z, aA[qp]);
            pair_acc(q2p[qp], q3p[qp], kAc.z, kAc.w, wp1.x, wp1.y, wp1.z, aA[qp]);
            pair_acc(q0p[qp], q1p[qp], kBc.x, kBc.y, wp0.x, wp0.y, wp0.z, aB[qp]);
            pair_acc(q2p[qp], q3p[qp], kBc.z, kBc.w, wp1.x, wp1.y, wp1.z, aB[qp]);
        }
    }

    if (qtr) {
        float4 vA0 = make_float4(aA[0].x, aA[0].y, aA[1].x, aA[1].y);
        float4 vA1 = make_float4(aA[2].x, aA[2].y, aA[3].x, aA[3].y);
        float4 vB0 = make_float4(aB[0].x, aB[0].y, aB[1].x, aB[1].y);
        float4 vB1 = make_float4(aB[2].x, aB[2].y, aB[3].x, aB[3].y);
        *(float4*)&pacc[qtr - 1][0][k16][0] = vA0;
        *(float4*)&pacc[qtr - 1][0][k16][4] = vA1;
        *(float4*)&pacc[qtr - 1][1][k16][0] = vB0;
        *(float4*)&pacc[qtr - 1][1][k16][4] = vB1;
    }
    __syncthreads();

    float e[2][QT];
    if (!qtr) {
        float s[2][QT];
        #pragma unroll
        for (int qp = 0; qp < 4; ++qp) {
            s[0][2*qp]   = aA[qp].x;
            s[0][2*qp+1] = aA[qp].y;
            s[1][2*qp]   = aB[qp].x;
            s[1][2*qp+1] = aB[qp].y;
        }
        #pragma unroll
        for (int o = 0; o < 3; ++o) {
            #pragma unroll
            for (int kk = 0; kk < 2; ++kk) {
                float4 t0 = *(const float4*)&pacc[o][kk][k16][0];
                float4 t1 = *(const float4*)&pacc[o][kk][k16][4];
                s[kk][0] += t0.x; s[kk][1] += t0.y; s[kk][2] += t0.z; s[kk][3] += t0.w;
                s[kk][4] += t1.x; s[kk][5] += t1.y; s[kk][6] += t1.z; s[kk][7] += t1.w;
            }
        }
        // softmax without max-pass: |2*acc| <= 2*sum|wv| ~ 26 -> fp32-safe
        #pragma unroll
        for (int kk = 0; kk < 2; ++kk)
            #pragma unroll
            for (int qq = 0; qq < QT; ++qq)
                e[kk][qq] = __builtin_amdgcn_exp2f(-SC2 * s[kk][qq]);
        #pragma unroll
        for (int qq = 0; qq < QT; ++qq) {
            float v = e[0][qq] + e[1][qq];
            #pragma unroll
            for (int off = 32; off; off >>= 1) v += __shfl_xor(v, off);
            if (lane == 0) red[tid >> 6][qq] = v;
        }
    }
    __syncthreads();
    if (!qtr) {
        #pragma unroll
        for (int qq = 0; qq < QT; ++qq) {
            float v = red[0][qq] + red[1][qq] + red[2][qq] + red[3][qq];
            float rv = __builtin_amdgcn_rcpf(v);
            #pragma unroll
            for (int kk = 0; kk < 2; ++kk) {
                float a = e[kk][qq] * rv;
                long long o = (long long)(b * Q_ + q0 + qq) * K_ + k16 + kk * 256;
                attn_out[o] = a;
                aB_hi[o] = brn(a);
            }
        }
    }
}

extern "C" void kernel_launch(void* const* d_in, const int* in_sizes, int n_in,
                              void* d_out, int out_size, void* d_ws, size_t ws_size,
                              hipStream_t stream) {
    const float* query = (const float*)d_in[0];
    const float* key   = (const float*)d_in[1];
    const float* value = (const float*)d_in[2];
    const float* Wq    = (const float*)d_in[3];
    const float* bq    = (const float*)d_in[4];
    const float* Wk    = (const float*)d_in[5];
    const float* bk    = (const float*)d_in[6];
    const float* wv    = (const float*)d_in[7];
    // bv cancels in softmax.

    float* out = (float*)d_out;
    float* ctx_out  = out;                              // [B,Q,DV]
    float* attn_out = out + (size_t)B_ * Q_ * DV_;      // [B,Q,K]

    float* ws   = (float*)d_ws;
    float* qp4  = ws;                                   // 524288 f (packed Eq)
    float* kT4  = qp4 + 524288;                         // 524288 f (packed Ek)
    u16* qA_hi  = (u16*)(kT4 + 524288);
    u16* kA_hi  = qA_hi + 1048576;
    u16* qA_lo  = kA_hi + 1048576;
    u16* kA_lo  = qA_lo + 1048576;
    u16* WqT_hi = kA_lo + 1048576;
    u16* WkT_hi = WqT_hi + 131072;
    u16* WqT_lo = WkT_hi + 131072;
    u16* WkT_lo = WqT_lo + 131072;
    u16* vT_hi  = WkT_lo + 131072;
    u16* aB_hi  = vT_hi + 1048576;
    (void)qA_lo; (void)WqT_lo; (void)n_in; (void)ws_size; (void)in_sizes; (void)out_size;

    hipLaunchKernelGGL(prep_all, dim3(3584), dim3(256), 0, stream,
                       query, key, Wq, Wk, value,
                       qA_hi, qA_lo, WqT_hi, WqT_lo, vT_hi);

    hipLaunchKernelGGL(proj_gemm, dim3(32, 4, 2), dim3(256), 0, stream,
                       qA_hi, qA_lo, WqT_hi, WqT_lo, bq, bk, qp4,
                       (long long)1048576, (long long)131072, (long long)524288);

    // MEASUREMENT: run score 3x (idempotent). Delta vs R16 = 2 x t_score(warm).
    hipLaunchKernelGGL(score_softmax, dim3(Q_ / QT, B_), dim3(1024), 0, stream,
                       qp4, kT4, wv, attn_out, aB_hi);
    hipLaunchKernelGGL(score_softmax, dim3(Q_ / QT, B_), dim3(1024), 0, stream,
                       qp4, kT4, wv, attn_out, aB_hi);
    hipLaunchKernelGGL(score_softmax, dim3(Q_ / QT, B_), dim3(1024), 0, stream,
                       qp4, kT4, wv, attn_out, aB_hi);

    hipLaunchKernelGGL(pv_gemm, dim3(8, 8, 4), dim3(256), 0, stream,
                       aB_hi, vT_hi, ctx_out);
}

// Round 20
// 60.262 us; speedup vs baseline: 1.9894x; 1.9894x over previous
//
#include <hip/hip_runtime.h>
#include <hip/hip_bf16.h>

#define B_ 4
#define Q_ 512
#define K_ 512
#define DQ_ 512
#define H_ 256
#define DV_ 512

#define SC2 2.8853900817779268f   // 2*log2(e): exp(2x) = exp2(SC2*x)

typedef unsigned short u16;
typedef short bf16x8 __attribute__((ext_vector_type(8)));
typedef float f32x4 __attribute__((ext_vector_type(4)));
typedef float f32x2 __attribute__((ext_vector_type(2)));
typedef unsigned short u16x4 __attribute__((ext_vector_type(4)));

// split fp32 a into bf16 hi/lo (RN both): a ~= hi + lo, packed [hi16|lo16]
__device__ __forceinline__ unsigned bsplit(float a) {
    unsigned u  = __float_as_uint(a);
    unsigned hi = (u + 0x7FFFu + ((u >> 16) & 1u)) >> 16;
    float hf = __uint_as_float(hi << 16);
    float l  = a - hf;
    unsigned ul = __float_as_uint(l);
    unsigned lo = (ul + 0x7FFFu + ((ul >> 16) & 1u)) >> 16;
    return (hi << 16) | lo;
}

// RN fp32 -> bf16 (hi only)
__device__ __forceinline__ u16 brn(float a) {
    unsigned u = __float_as_uint(a);
    return (u16)((u + 0x7FFFu + ((u >> 16) & 1u)) >> 16);
}

__device__ __forceinline__ void gld16(const void* g, void* l) {
    __builtin_amdgcn_global_load_lds(
        (const __attribute__((address_space(1))) unsigned int*)g,
        (__attribute__((address_space(3))) unsigned int*)l, 16, 0, 0);
}

// pair of h-terms over common denominator (R16 builtin version, known-good):
// w0/(1+e0) + w1/(1+e1) = (w01 + w0*e1 + w1*e0) / (1 + e0 + e1 + e0*e1)
__device__ __forceinline__ void pair_acc(
    f32x2 Eq0, f32x2 Eq1, float ek0, float ek1,
    float w0, float w1, float w01, f32x2& acc)
{
    f32x2 e0 = Eq0 * (f32x2){ek0, ek0};
    f32x2 e1 = Eq1 * (f32x2){ek1, ek1};
    f32x2 s  = e0 + e1;
    f32x2 den = __builtin_elementwise_fma(e0, e1, s);
    den = den + (f32x2){1.f, 1.f};
    f32x2 num = __builtin_elementwise_fma(e1, (f32x2){w0, w0}, (f32x2){w01, w01});
    num = __builtin_elementwise_fma(e0, (f32x2){w1, w1}, num);
    f32x2 r = {__builtin_amdgcn_rcpf(den.x), __builtin_amdgcn_rcpf(den.y)};
    acc = __builtin_elementwise_fma(num, r, acc);
}

// ============ merged prep: rows-convert + transposes in ONE launch ============
// rows: query/key -> bf16 HI ONLY (proj A-side is bf16x1 now)
__global__ __launch_bounds__(256) void prep_all(
    const float* __restrict__ query, const float* __restrict__ key,
    const float* __restrict__ Wq, const float* __restrict__ Wk,
    const float* __restrict__ value,
    u16* __restrict__ qA_hi,
    u16* __restrict__ WT_hi, u16* __restrict__ WT_lo,
    u16* __restrict__ vT_hi)
{
    const int bx  = blockIdx.x;
    const int tid = threadIdx.x;

    if (bx < 2048) {
        const int z = bx >> 10;
        const float* src = z ? key : query;
        u16* dh = qA_hi + (long long)z * 1048576;
        long long i4 = (long long)(bx & 1023) * 256 + tid;
        float4 v = ((const float4*)src)[i4];
        u16x4 h4 = {brn(v.x), brn(v.y), brn(v.z), brn(v.w)};
        *(u16x4*)(dh + i4 * 4) = h4;
        return;
    }

    __shared__ float t[32][33];
    const int flat = bx - 2048;
    const int z  = flat >> 8;            // 0..5
    const int rem = flat & 255;
    const int gx = rem & 15, gy = rem >> 4;
    const int x = tid & 31, y = tid >> 5;
    const float* src; u16 *dh, *dl; int C;
    if (z < 2) {
        if (gy >= 8) return;
        src = z ? Wk : Wq; C = 256;
        dh = WT_hi + (long long)z * 131072;
        dl = WT_lo + (long long)z * 131072;
    } else {
        src = value + (long long)(z - 2) * 262144; C = 512;
        dh = vT_hi + (long long)(z - 2) * 262144;
        dl = nullptr;                    // value: bf16 hi only (PV is 1-MFMA)
    }
    const int r0 = gx * 32, c0 = gy * 32;
    #pragma unroll
    for (int i = 0; i < 32; i += 8)
        t[y + i][x] = src[(long long)(r0 + y + i) * C + c0 + x];
    __syncthreads();
    {
        const int r = tid >> 3, c = tid & 7;
        long long o = (long long)(c0 + r) * 512 + r0 + 4 * c;
        if (dl) {
            unsigned p0 = bsplit(t[4 * c + 0][r]);
            unsigned p1 = bsplit(t[4 * c + 1][r]);
            unsigned p2 = bsplit(t[4 * c + 2][r]);
            unsigned p3 = bsplit(t[4 * c + 3][r]);
            u16x4 h4 = {(u16)(p0 >> 16), (u16)(p1 >> 16), (u16)(p2 >> 16), (u16)(p3 >> 16)};
            u16x4 l4 = {(u16)(p0 & 0xFFFF), (u16)(p1 & 0xFFFF), (u16)(p2 & 0xFFFF), (u16)(p3 & 0xFFFF)};
            *(u16x4*)(dh + o) = h4;
            *(u16x4*)(dl + o) = l4;
        } else {
            u16x4 h4 = {brn(t[4 * c + 0][r]), brn(t[4 * c + 1][r]),
                        brn(t[4 * c + 2][r]), brn(t[4 * c + 3][r])};
            *(u16x4*)(dh + o) = h4;
        }
    }
}

// ============ proj GEMM — A bf16x1, B bf16x2 (hi+lo): 2 MFMA per fragment ============
// z=0: q-proj -> qp4E packed [(row>>2)*H + h][row&3] = exp2(SC2*(A.B+bias))
// z=1: k-proj -> kT4E packed [b][h>>2][k][h&3]       = exp2(SC2*(A.B+bias))
__global__ __launch_bounds__(256) void proj_gemm(
    const u16* __restrict__ Ah0,
    const u16* __restrict__ Bh0, const u16* __restrict__ Bl0,
    const float* __restrict__ biasq, const float* __restrict__ biask,
    float* __restrict__ outp,
    long long sA, long long sB, long long sO)
{
    const int z = blockIdx.z;
    const int Kd = DQ_;
    const u16* Ah = Ah0 + z * sA;
    const u16* Bh = Bh0 + z * sB;
    const u16* Bl = Bl0 + z * sB;

    const int m0 = blockIdx.x * 64;
    const int n0 = blockIdx.y * 64;

    __shared__ u16 AhS[2][64 * 64], BhS[2][64 * 64], BlS[2][64 * 64];

    const int tid = threadIdx.x;
    const int lane = tid & 63, w = tid >> 6;
    const int wr = w >> 1, wc = w & 1;
    const int lrow = lane & 15, lgrp = lane >> 4;

    f32x4 acc[2][2] = {};

    const int idx0 = tid, idx1 = tid + 256;
    const int row0 = idx0 >> 3, u0 = idx0 & 7;
    const int row1 = idx1 >> 3, u1 = idx1 & 7;
    const long long goA0 = (long long)(m0 + row0) * Kd + ((u0 ^ (row0 & 7)) << 3);
    const long long goA1 = (long long)(m0 + row1) * Kd + ((u1 ^ (row1 & 7)) << 3);
    const long long goB0 = (long long)(n0 + row0) * Kd + ((u0 ^ (row0 & 7)) << 3);
    const long long goB1 = (long long)(n0 + row1) * Kd + ((u1 ^ (row1 & 7)) << 3);

#define STAGE(BI, K0) do {                                    \
        gld16(Ah + goA0 + (K0), &AhS[BI][idx0 * 8]);          \
        gld16(Bh + goB0 + (K0), &BhS[BI][idx0 * 8]);          \
        gld16(Bl + goB0 + (K0), &BlS[BI][idx0 * 8]);          \
        gld16(Ah + goA1 + (K0), &AhS[BI][idx1 * 8]);          \
        gld16(Bh + goB1 + (K0), &BhS[BI][idx1 * 8]);          \
        gld16(Bl + goB1 + (K0), &BlS[BI][idx1 * 8]);          \
    } while (0)

    STAGE(0, 0);
    __syncthreads();

    int cur = 0;
    for (int k0 = 0; k0 < Kd; k0 += 64) {
        if (k0 + 64 < Kd) STAGE(cur ^ 1, k0 + 64);

        #pragma unroll
        for (int kk = 0; kk < 2; ++kk) {
            bf16x8 ah[2], bh[2], bl[2];
            #pragma unroll
            for (int f = 0; f < 2; ++f) {
                int ar = wr * 32 + f * 16 + lrow;
                int au = (kk * 4 + lgrp) ^ (ar & 7);
                ah[f] = *(const bf16x8*)(&AhS[cur][ar * 64 + au * 8]);
                int br = wc * 32 + f * 16 + lrow;
                int bu = (kk * 4 + lgrp) ^ (br & 7);
                bh[f] = *(const bf16x8*)(&BhS[cur][br * 64 + bu * 8]);
                bl[f] = *(const bf16x8*)(&BlS[cur][br * 64 + bu * 8]);
            }
            #pragma unroll
            for (int fm = 0; fm < 2; ++fm)
                #pragma unroll
                for (int fn = 0; fn < 2; ++fn) {
                    acc[fm][fn] = __builtin_amdgcn_mfma_f32_16x16x32_bf16(ah[fm], bh[fn], acc[fm][fn], 0, 0, 0);
                    acc[fm][fn] = __builtin_amdgcn_mfma_f32_16x16x32_bf16(ah[fm], bl[fn], acc[fm][fn], 0, 0, 0);
                }
        }
        __syncthreads();
        cur ^= 1;
    }
#undef STAGE

    const float* bs = z ? biask : biasq;
    #pragma unroll
    for (int fm = 0; fm < 2; ++fm)
        #pragma unroll
        for (int fn = 0; fn < 2; ++fn)
            #pragma unroll
            for (int r = 0; r < 4; ++r) {
                int m = m0 + wr * 32 + fm * 16 + lgrp * 4 + r;
                int n = n0 + wc * 32 + fn * 16 + lrow;
                float v = __builtin_amdgcn_exp2f((acc[fm][fn][r] + bs[n]) * SC2);
                if (z == 0) {
                    outp[(((long long)(m >> 2) * H_ + n) << 2) + (m & 3)] = v;
                } else {
                    int bb = m >> 9, k = m & 511;
                    outp[sO + (((long long)(bb * 64 + (n >> 2)) * 512 + k) << 2) + (n & 3)] = v;
                }
            }
}

// ============ PV GEMM — single bf16 MFMA ============
__global__ __launch_bounds__(256) void pv_gemm(
    const u16* __restrict__ A0, const u16* __restrict__ B0,
    float* __restrict__ ctx)
{
    const int z = blockIdx.z;
    const int Kd = K_;
    const u16* A = A0 + (long long)z * 262144;
    const u16* Bp = B0 + (long long)z * 262144;
    float* C = ctx + (long long)z * 262144;

    const int m0 = blockIdx.x * 64;
    const int n0 = blockIdx.y * 64;

    __shared__ u16 AS[2][64 * 64], BS[2][64 * 64];

    const int tid = threadIdx.x;
    const int lane = tid & 63, w = tid >> 6;
    const int wr = w >> 1, wc = w & 1;
    const int lrow = lane & 15, lgrp = lane >> 4;

    f32x4 acc[2][2] = {};

    const int idx0 = tid, idx1 = tid + 256;
    const int row0 = idx0 >> 3, u0 = idx0 & 7;
    const int row1 = idx1 >> 3, u1 = idx1 & 7;
    const long long goA0 = (long long)(m0 + row0) * Kd + ((u0 ^ (row0 & 7)) << 3);
    const long long goA1 = (long long)(m0 + row1) * Kd + ((u1 ^ (row1 & 7)) << 3);
    const long long goB0 = (long long)(n0 + row0) * Kd + ((u0 ^ (row0 & 7)) << 3);
    const long long goB1 = (long long)(n0 + row1) * Kd + ((u1 ^ (row1 & 7)) << 3);

#define STAGE(BI, K0) do {                                    \
        gld16(A  + goA0 + (K0), &AS[BI][idx0 * 8]);           \
        gld16(Bp + goB0 + (K0), &BS[BI][idx0 * 8]);           \
        gld16(A  + goA1 + (K0), &AS[BI][idx1 * 8]);           \
        gld16(Bp + goB1 + (K0), &BS[BI][idx1 * 8]);           \
    } while (0)

    STAGE(0, 0);
    __syncthreads();

    int cur = 0;
    for (int k0 = 0; k0 < Kd; k0 += 64) {
        if (k0 + 64 < Kd) STAGE(cur ^ 1, k0 + 64);

        #pragma unroll
        for (int kk = 0; kk < 2; ++kk) {
            bf16x8 a[2], b[2];
            #pragma unroll
            for (int f = 0; f < 2; ++f) {
                int ar = wr * 32 + f * 16 + lrow;
                int au = (kk * 4 + lgrp) ^ (ar & 7);
                a[f] = *(const bf16x8*)(&AS[cur][ar * 64 + au * 8]);
                int br = wc * 32 + f * 16 + lrow;
                int bu = (kk * 4 + lgrp) ^ (br & 7);
                b[f] = *(const bf16x8*)(&BS[cur][br * 64 + bu * 8]);
            }
            #pragma unroll
            for (int fm = 0; fm < 2; ++fm)
                #pragma unroll
                for (int fn = 0; fn < 2; ++fn)
                    acc[fm][fn] = __builtin_amdgcn_mfma_f32_16x16x32_bf16(a[fm], b[fn], acc[fm][fn], 0, 0, 0);
        }
        __syncthreads();
        cur ^= 1;
    }
#undef STAGE

    #pragma unroll
    for (int fm = 0; fm < 2; ++fm)
        #pragma unroll
        for (int fn = 0; fn < 2; ++fn)
            #pragma unroll
            for (int r = 0; r < 4; ++r) {
                int m = m0 + wr * 32 + fm * 16 + lgrp * 4 + r;
                int n = n0 + wc * 32 + fn * 16 + lrow;
                C[(long long)m * DV_ + n] = acc[fm][fn][r];
            }
}

// ============ fused score + softmax: QT=8 (R16 builtin version, known-good) ============
#define QT 8

__global__ __launch_bounds__(1024) void score_softmax(
    const float* __restrict__ qp4E, // [(B*Q)/4][H][4] = exp2(SC2*qproj)
    const float* __restrict__ kT4E, // [B][H/4][K][4]  = exp2(SC2*kproj)
    const float* __restrict__ wv,   // [H]
    float* __restrict__ attn_out,   // [B*Q][K] fp32
    u16* __restrict__ aB_hi)        // attn bf16 for PV
{
    const int b   = blockIdx.y;
    const int q0  = blockIdx.x * QT;
    const int tid = threadIdx.x;          // 0..1023
    const int k16 = tid & 255;
    const int qtr = tid >> 8;             // h-quarter 0..3
    const int lane = tid & 63;

    __shared__ float lq[H_][8];           // Eq broadcast: [h][q 0..7] (8KB)
    __shared__ float lwp[H_ / 2][4];      // {w0,w1,w0+w1,0} per h-pair (2KB)
    __shared__ float pacc[3][2][256][8];  // 48KB: [quarter-1][kk][k16][qq]
    __shared__ float red[4][QT];          // 128B

    if (tid < 256) {
        const float4* qA = (const float4*)qp4E + ((long long)(b * (Q_ / 4) + 2 * blockIdx.x)) * H_;
        *(float4*)&lq[tid][0] = qA[tid];
    } else if (tid < 512) {
        int h = tid - 256;
        const float4* qB = (const float4*)qp4E + ((long long)(b * (Q_ / 4) + 2 * blockIdx.x + 1)) * H_;
        *(float4*)&lq[h][4] = qB[h];
    } else if (tid < 512 + 128) {
        int p = tid - 512;
        float w0 = wv[2 * p], w1 = wv[2 * p + 1];
        lwp[p][0] = w0; lwp[p][1] = w1; lwp[p][2] = w0 + w1; lwp[p][3] = 0.f;
    }
    __syncthreads();

    f32x2 aA[4] = {{0.f,0.f},{0.f,0.f},{0.f,0.f},{0.f,0.f}};
    f32x2 aB[4] = {{0.f,0.f},{0.f,0.f},{0.f,0.f},{0.f,0.f}};
    const float4* kvec = (const float4*)kT4E + (long long)b * (H_ / 4) * K_ + k16;
    const int g0 = qtr * 16;

    float4 kA = kvec[(long long)g0 * K_];
    float4 kB = kvec[(long long)g0 * K_ + 256];
    #pragma unroll 2
    for (int gi = 0; gi < 16; ++gi) {
        const int g = g0 + gi;
        float4 kAc = kA, kBc = kB;
        if (gi < 15) {                                  // 1-deep prefetch
            kA = kvec[(long long)(g + 1) * K_];
            kB = kvec[(long long)(g + 1) * K_ + 256];
        }
        float4 wp0 = *(const float4*)&lwp[(g << 1) + 0][0];
        float4 wp1 = *(const float4*)&lwp[(g << 1) + 1][0];

        float4 qa0 = *(const float4*)&lq[(g << 2) + 0][0];
        float4 qb0 = *(const float4*)&lq[(g << 2) + 0][4];
        float4 qa1 = *(const float4*)&lq[(g << 2) + 1][0];
        float4 qb1 = *(const float4*)&lq[(g << 2) + 1][4];
        float4 qa2 = *(const float4*)&lq[(g << 2) + 2][0];
        float4 qb2 = *(const float4*)&lq[(g << 2) + 2][4];
        float4 qa3 = *(const float4*)&lq[(g << 2) + 3][0];
        float4 qb3 = *(const float4*)&lq[(g << 2) + 3][4];

        f32x2 q0p[4] = {{qa0.x,qa0.y},{qa0.z,qa0.w},{qb0.x,qb0.y},{qb0.z,qb0.w}};
        f32x2 q1p[4] = {{qa1.x,qa1.y},{qa1.z,qa1.w},{qb1.x,qb1.y},{qb1.z,qb1.w}};
        f32x2 q2p[4] = {{qa2.x,qa2.y},{qa2.z,qa2.w},{qb2.x,qb2.y},{qb2.z,qb2.w}};
        f32x2 q3p[4] = {{qa3.x,qa3.y},{qa3.z,qa3.w},{qb3.x,qb3.y},{qb3.z,qb3.w}};

        #pragma unroll
        for (int qp = 0; qp < 4; ++qp) {
            pair_acc(q0p[qp], q1p[qp], kAc.x, kAc.y, wp0.x, wp0.y, wp0.z, aA[qp]);
            pair_acc(q2p[qp], q3p[qp], kAc.z, kAc.w, wp1.x, wp1.y, wp1.z, aA[qp]);
            pair_acc(q0p[qp], q1p[qp], kBc.x, kBc.y, wp0.x, wp0.y, wp0.z, aB[qp]);
            pair_acc(q2p[qp], q3p[qp], kBc.z, kBc.w, wp1.x, wp1.y, wp1.z, aB[qp]);
        }
    }

    if (qtr) {
        float4 vA0 = make_float4(aA[0].x, aA[0].y, aA[1].x, aA[1].y);
        float4 vA1 = make_float4(aA[2].x, aA[2].y, aA[3].x, aA[3].y);
        float4 vB0 = make_float4(aB[0].x, aB[0].y, aB[1].x, aB[1].y);
        float4 vB1 = make_float4(aB[2].x, aB[2].y, aB[3].x, aB[3].y);
        *(float4*)&pacc[qtr - 1][0][k16][0] = vA0;
        *(float4*)&pacc[qtr - 1][0][k16][4] = vA1;
        *(float4*)&pacc[qtr - 1][1][k16][0] = vB0;
        *(float4*)&pacc[qtr - 1][1][k16][4] = vB1;
    }
    __syncthreads();

    float e[2][QT];
    if (!qtr) {
        float s[2][QT];
        #pragma unroll
        for (int qp = 0; qp < 4; ++qp) {
            s[0][2*qp]   = aA[qp].x;
            s[0][2*qp+1] = aA[qp].y;
            s[1][2*qp]   = aB[qp].x;
            s[1][2*qp+1] = aB[qp].y;
        }
        #pragma unroll
        for (int o = 0; o < 3; ++o) {
            #pragma unroll
            for (int kk = 0; kk < 2; ++kk) {
                float4 t0 = *(const float4*)&pacc[o][kk][k16][0];
                float4 t1 = *(const float4*)&pacc[o][kk][k16][4];
                s[kk][0] += t0.x; s[kk][1] += t0.y; s[kk][2] += t0.z; s[kk][3] += t0.w;
                s[kk][4] += t1.x; s[kk][5] += t1.y; s[kk][6] += t1.z; s[kk][7] += t1.w;
            }
        }
        // softmax without max-pass: |2*acc| <= 2*sum|wv| ~ 26 -> fp32-safe
        #pragma unroll
        for (int kk = 0; kk < 2; ++kk)
            #pragma unroll
            for (int qq = 0; qq < QT; ++qq)
                e[kk][qq] = __builtin_amdgcn_exp2f(-SC2 * s[kk][qq]);
        #pragma unroll
        for (int qq = 0; qq < QT; ++qq) {
            float v = e[0][qq] + e[1][qq];
            #pragma unroll
            for (int off = 32; off; off >>= 1) v += __shfl_xor(v, off);
            if (lane == 0) red[tid >> 6][qq] = v;
        }
    }
    __syncthreads();
    if (!qtr) {
        #pragma unroll
        for (int qq = 0; qq < QT; ++qq) {
            float v = red[0][qq] + red[1][qq] + red[2][qq] + red[3][qq];
            float rv = __builtin_amdgcn_rcpf(v);
            #pragma unroll
            for (int kk = 0; kk < 2; ++kk) {
                float a = e[kk][qq] * rv;
                long long o = (long long)(b * Q_ + q0 + qq) * K_ + k16 + kk * 256;
                attn_out[o] = a;
                aB_hi[o] = brn(a);
            }
        }
    }
}

extern "C" void kernel_launch(void* const* d_in, const int* in_sizes, int n_in,
                              void* d_out, int out_size, void* d_ws, size_t ws_size,
                              hipStream_t stream) {
    const float* query = (const float*)d_in[0];
    const float* key   = (const float*)d_in[1];
    const float* value = (const float*)d_in[2];
    const float* Wq    = (const float*)d_in[3];
    const float* bq    = (const float*)d_in[4];
    const float* Wk    = (const float*)d_in[5];
    const float* bk    = (const float*)d_in[6];
    const float* wv    = (const float*)d_in[7];
    // bv cancels in softmax.

    float* out = (float*)d_out;
    float* ctx_out  = out;                              // [B,Q,DV]
    float* attn_out = out + (size_t)B_ * Q_ * DV_;      // [B,Q,K]

    float* ws   = (float*)d_ws;
    float* qp4  = ws;                                   // 524288 f (packed Eq)
    float* kT4  = qp4 + 524288;                         // 524288 f (packed Ek)
    u16* qA_hi  = (u16*)(kT4 + 524288);                 // 1048576 (q) + 1048576 (k)
    u16* WqT_hi = qA_hi + 2097152;                      // 131072 x2 (Wq,Wk)
    u16* WqT_lo = WqT_hi + 262144;                      // 131072 x2
    u16* vT_hi  = WqT_lo + 262144;                      // 1048576
    u16* aB_hi  = vT_hi + 1048576;                      // 1048576
    (void)n_in; (void)ws_size; (void)in_sizes; (void)out_size;

    hipLaunchKernelGGL(prep_all, dim3(3584), dim3(256), 0, stream,
                       query, key, Wq, Wk, value,
                       qA_hi, WqT_hi, WqT_lo, vT_hi);

    hipLaunchKernelGGL(proj_gemm, dim3(32, 4, 2), dim3(256), 0, stream,
                       qA_hi, WqT_hi, WqT_lo, bq, bk, qp4,
                       (long long)1048576, (long long)131072, (long long)524288);

    hipLaunchKernelGGL(score_softmax, dim3(Q_ / QT, B_), dim3(1024), 0, stream,
                       qp4, kT4, wv, attn_out, aB_hi);

    hipLaunchKernelGGL(pv_gemm, dim3(8, 8, 4), dim3(256), 0, stream,
                       aB_hi, vT_hi, ctx_out);
}